// Round 11
// baseline (316.759 us; speedup 1.0000x reference)
//
#include <hip/hip_runtime.h>
#include <hip/hip_bf16.h>
#include <stdint.h>

#define NN 16384
#define BM 64
#define BKA 128              // A staged k-depth: 512 B per row per burst
#define BKB 64               // compute / B substep k-depth
#define NGROUPS (NN / BKA)   // 128
#define NKT (NN / BKB)       // 256

typedef __attribute__((ext_vector_type(8))) short bf16x8;   // MFMA A/B frag
typedef __attribute__((ext_vector_type(4))) float f32x4;
typedef __attribute__((ext_vector_type(4))) unsigned short u16x4;
typedef __attribute__((ext_vector_type(8))) unsigned short u16x8;
typedef __attribute__((ext_vector_type(4))) unsigned int u32x4;

__device__ __forceinline__ unsigned short f2bf(float f) {
    uint32_t u = __builtin_bit_cast(uint32_t, f);
    u += 0x7fffu + ((u >> 16) & 1u);   // RNE; inputs are finite
    return (unsigned short)(u >> 16);
}

// Tiled transpose: neighT[c][r] = bf16(neigh[r][c]). Coalesced reads AND writes.
__global__ __launch_bounds__(256) void prep_transpose(const float* __restrict__ src,
                                                      unsigned short* __restrict__ dstT) {
    __shared__ unsigned short tl[128][66];
    const int t = threadIdx.x;
    const int r0 = blockIdx.x * 64;
#pragma unroll
    for (int i = 0; i < 8; ++i) {
        int idx = i * 256 + t;
        int r = idx >> 5;
        int s = idx & 31;
        f32x4 v = *(const f32x4*)(src + (size_t)(r0 + r) * 128 + s * 4);
#pragma unroll
        for (int j = 0; j < 4; ++j) tl[s * 4 + j][r] = f2bf(v[j]);
    }
    __syncthreads();
    const int c = t >> 1;
    const int half = t & 1;
#pragma unroll
    for (int j = 0; j < 4; ++j) {
        u16x8 p;
#pragma unroll
        for (int e = 0; e < 8; ++e) p[e] = tl[c][half * 32 + j * 8 + e];
        *(u16x8*)(dstT + (size_t)c * NN + r0 + half * 32 + j * 8) = p;
    }
}

#define MFMA16(a, b, c) __builtin_amdgcn_mfma_f32_16x16x32_bf16(a, b, c, 0, 0, 0)

// Raw barrier: ds_writes visible (lgkmcnt only); global loads stay in flight.
#define BARRIER() do {                                          \
    asm volatile("s_waitcnt lgkmcnt(0)" ::: "memory");          \
    __builtin_amdgcn_s_barrier();                               \
    __builtin_amdgcn_sched_barrier(0);                          \
} while (0)

__global__ __launch_bounds__(256, 1) void sage_fused(
    const float* __restrict__ adj,
    const float* __restrict__ feat,
    const unsigned short* __restrict__ neighT,
    const float* __restrict__ W,
    float* __restrict__ out)
{
    // LDS 64.3 KB, 1 block/CU (grid = 256 = CU count).
    //  aL: [2][64 rows][256 B] bf16 swizzled (A, k-depth 128) = 32 KB
    //  bL: [2][128 rows][128 B] bf16 swizzled (B, k-depth 64) = 32 KB
    //  dL: epilogue [64][512 B] aliases front 32 KB; degp at tail.
    __shared__ __align__(16) char smem[65792];
    char* aL = smem;
    char* bL = smem + 32768;
    char* dL = smem;
    float* degp = (float*)(smem + 65536);

    const int t = threadIdx.x;
    const int lane = t & 63;
    const int wv = t >> 6;        // wave 0..3
    const int mt = wv >> 1;       // wave row-group: rows mt*32..+32
    const int nt = wv & 1;        // wave col-group: cols nt*64..+64
    const size_t row0 = (size_t)blockIdx.x * BM;

    // ---- A staging: 4 lanes per row; row ra = t>>2, lane slot asl = t&3.
    // Load i covers f32 k = asl*4 + i*16 (+4): the 4-lane group sweeps the
    // row contiguously in 64-B units -> 512-B burst per row per group.
    const int ra = t >> 2;
    const int asl = t & 3;
    const float* aGa = adj + (row0 + ra) * (size_t)NN + asl * 4;

    int awz[8];
#pragma unroll
    for (int i = 0; i < 8; ++i)
        awz[i] = ra * 256 + ((i * 32 + asl * 8) ^ ((ra & 7) << 4));

    // ---- B staging: 4 passes of 32 rows; row br0 = t>>3, slot bcs.
    const int br0 = t >> 3;
    const int bcs = (t & 7) * 8;
    const unsigned short* bG = neighT + (size_t)br0 * NN + bcs;
    int bwb[4];
#pragma unroll
    for (int i = 0; i < 4; ++i) {
        int br = br0 + 32 * i;
        bwb[i] = (br * 128 + bcs * 2) ^ ((br & 7) << 4);
    }

    f32x4 acc[2][4];
#pragma unroll
    for (int i = 0; i < 2; ++i)
#pragma unroll
        for (int j = 0; j < 4; ++j) acc[i][j] = (f32x4){0.f, 0.f, 0.f, 0.f};

    float dsum = 0.f;

    f32x4 arA[8];
    u32x4 br_[4];

#define ISSUE_A(G) do {                                                       \
    _Pragma("unroll")                                                         \
    for (int i = 0; i < 8; ++i)                                               \
        arA[i] = __builtin_nontemporal_load(                                  \
            (const f32x4*)(aGa + (size_t)(G) * BKA + i * 16));                \
} while (0)

#define ISSUE_B(KT) do {                                                      \
    _Pragma("unroll")                                                         \
    for (int i = 0; i < 4; ++i)                                               \
        br_[i] = *(const u32x4*)(bG + (size_t)(32 * i) * NN +                 \
                                 (size_t)(KT) * BKB);                         \
} while (0)

#define STAGE_A(DST) do {                                                     \
    _Pragma("unroll")                                                         \
    for (int i = 0; i < 8; ++i) {                                             \
        f32x4 v = arA[i];                                                     \
        dsum += (v[0] + v[1]) + (v[2] + v[3]);                                \
        u16x4 p; p.x = f2bf(v[0]); p.y = f2bf(v[1]);                          \
        p.z = f2bf(v[2]); p.w = f2bf(v[3]);                                   \
        *(u16x4*)((DST) + awz[i]) = p;                                        \
    }                                                                         \
} while (0)

#define STAGE_B(BUF) do {                                                     \
    char* bW = bL + (BUF) * 16384;                                            \
    _Pragma("unroll")                                                         \
    for (int i = 0; i < 4; ++i)                                               \
        *(u32x4*)(bW + bwb[i]) = br_[i];                                      \
} while (0)

#define COMPUTE(ABASE, SUB, BBUF) do {                                        \
    const char* aB = (ABASE);                                                 \
    const char* bB = bL + (BBUF) * 16384;                                     \
    _Pragma("unroll")                                                         \
    for (int ks = 0; ks < 2; ++ks) {                                          \
        bf16x8 af[2], bfr[4];                                                 \
        _Pragma("unroll")                                                     \
        for (int ms = 0; ms < 2; ++ms) {                                      \
            int r = mt * 32 + ms * 16 + (lane & 15);                          \
            int off = r * 256 + (((SUB) * 128 + ks * 64 + (lane >> 4) * 16)   \
                      ^ ((r & 7) << 4));                                      \
            af[ms] = *(const bf16x8*)(aB + off);                              \
        }                                                                     \
        _Pragma("unroll")                                                     \
        for (int ns = 0; ns < 4; ++ns) {                                      \
            int c = nt * 64 + ns * 16 + (lane & 15);                          \
            int off = c * 128 + ((ks * 64 + (lane >> 4) * 16)                 \
                      ^ ((c & 7) << 4));                                      \
            bfr[ns] = *(const bf16x8*)(bB + off);                             \
        }                                                                     \
        _Pragma("unroll")                                                     \
        for (int ms = 0; ms < 2; ++ms)                                        \
            _Pragma("unroll")                                                 \
            for (int ns = 0; ns < 4; ++ns)                                    \
                acc[ms][ns] = MFMA16(af[ms], bfr[ns], acc[ms][ns]);           \
    }                                                                         \
} while (0)

    // prologue: stage group 0 / substep 0 (one-time latency stall)
    ISSUE_B(0);
    ISSUE_A(0);
    STAGE_B(0);
    STAGE_A(aL);
    BARRIER();

    // steady state: group g = 2 substeps over A-tile g (k = g*128).
    for (int g = 0; g < NGROUPS; ++g) {
        char* aCur = aL + (g & 1) * 16384;
        char* aNxt = aL + ((g & 1) ^ 1) * 16384;
#pragma unroll
        for (int s = 0; s < 2; ++s) {
            const int kt = g * 2 + s;
            if (kt + 1 < NKT) ISSUE_B(kt + 1);
            if (s == 0 && g + 1 < NGROUPS) ISSUE_A(g + 1);
            COMPUTE(aCur, s, kt & 1);
            if (kt + 1 < NKT) STAGE_B((kt + 1) & 1);
            if (s == 1 && g + 1 < NGROUPS) STAGE_A(aNxt);
            BARRIER();
        }
    }

    // ---- degree: 4-lane shfl tree (threads 4r..4r+3 share row r) ----
    dsum += __shfl_xor(dsum, 1, 64);
    dsum += __shfl_xor(dsum, 2, 64);
    if (asl == 0) degp[ra] = dsum;
    __syncthreads();   // full drain; also fences before dL aliases aL

    // ---- h = S/deg -> dL cols [128,256) ----
#pragma unroll
    for (int ms = 0; ms < 2; ++ms)
#pragma unroll
        for (int ns = 0; ns < 4; ++ns)
#pragma unroll
            for (int j = 0; j < 4; ++j) {
                int r = mt * 32 + ms * 16 + (lane >> 4) * 4 + j;
                int c = 128 + nt * 64 + ns * 16 + (lane & 15);
                float v = acc[ms][ns][j] / (degp[r] + 1.0f);
                int off = (r * 512 + c * 2) ^ ((r & 7) << 4);
                *(unsigned short*)(dL + off) = f2bf(v);
            }

    // ---- features -> dL cols [0,128) ----
#pragma unroll
    for (int i = 0; i < 8; ++i) {
        int idx = i * 256 + t;
        int r = idx >> 5;          // 32 f32x4-slots per 128-f32 row
        int s = idx & 31;
        f32x4 v = *(const f32x4*)(feat + (row0 + r) * 128 + s * 4);
        u16x4 p; p.x = f2bf(v[0]); p.y = f2bf(v[1]); p.z = f2bf(v[2]); p.w = f2bf(v[3]);
        int off = (r * 512 + s * 8) ^ ((r & 7) << 4);
        *(u16x4*)(dL + off) = p;
    }
    __syncthreads();

    // ---- out = data(64x256) @ W^T via MFMA, K=256; W frags from global f32 ----
    f32x4 acc2[2][4];
#pragma unroll
    for (int i = 0; i < 2; ++i)
#pragma unroll
        for (int j = 0; j < 4; ++j) acc2[i][j] = (f32x4){0.f, 0.f, 0.f, 0.f};

#pragma unroll
    for (int ks = 0; ks < 8; ++ks) {
        bf16x8 af[2], bfr[4];
#pragma unroll
        for (int ms = 0; ms < 2; ++ms) {
            int r = mt * 32 + ms * 16 + (lane & 15);
            int off = r * 512 + ((ks * 64 + (lane >> 4) * 16) ^ ((r & 7) << 4));
            af[ms] = *(const bf16x8*)(dL + off);
        }
#pragma unroll
        for (int ns = 0; ns < 4; ++ns) {
            int c = nt * 64 + ns * 16 + (lane & 15);
            int k0 = ks * 32 + (lane >> 4) * 8;
            f32x4 w0 = *(const f32x4*)(W + (size_t)c * 256 + k0);
            f32x4 w1 = *(const f32x4*)(W + (size_t)c * 256 + k0 + 4);
            u16x8 p;
            p[0] = f2bf(w0[0]); p[1] = f2bf(w0[1]); p[2] = f2bf(w0[2]); p[3] = f2bf(w0[3]);
            p[4] = f2bf(w1[0]); p[5] = f2bf(w1[1]); p[6] = f2bf(w1[2]); p[7] = f2bf(w1[3]);
            bfr[ns] = __builtin_bit_cast(bf16x8, p);
        }
#pragma unroll
        for (int ms = 0; ms < 2; ++ms)
#pragma unroll
            for (int ns = 0; ns < 4; ++ns)
                acc2[ms][ns] = MFMA16(af[ms], bfr[ns], acc2[ms][ns]);
    }

    // ---- store f32 ----
#pragma unroll
    for (int ms = 0; ms < 2; ++ms)
#pragma unroll
        for (int ns = 0; ns < 4; ++ns)
#pragma unroll
            for (int j = 0; j < 4; ++j) {
                int r = mt * 32 + ms * 16 + (lane >> 4) * 4 + j;
                int c = nt * 64 + ns * 16 + (lane & 15);
                out[(row0 + r) * 128 + c] = acc2[ms][ns][j];
            }
}

extern "C" void kernel_launch(void* const* d_in, const int* in_sizes, int n_in,
                              void* d_out, int out_size, void* d_ws, size_t ws_size,
                              hipStream_t stream) {
    const float* adj = (const float*)d_in[0];
    const float* feat = (const float*)d_in[1];
    const float* neigh = (const float*)d_in[2];
    const float* W = (const float*)d_in[3];
    float* out = (float*)d_out;
    unsigned short* neighT = (unsigned short*)d_ws;   // 128 x 16384 bf16 = 4 MiB

    prep_transpose<<<NN / 64, 256, 0, stream>>>(neigh, neighT);
    sage_fused<<<NN / BM, 256, 0, stream>>>(adj, feat, neighT, W, out);
}

// Round 12
// 233.060 us; speedup vs baseline: 1.3591x; 1.3591x over previous
//
#include <hip/hip_runtime.h>
#include <hip/hip_bf16.h>
#include <stdint.h>

#define NN 16384
#define BM 64
#define KHALF 8192
#define BKA 128              // A staged k-depth per group
#define BKB 64               // compute / B substep k-depth
#define NG1 (KHALF / BKA)    // 64 groups per block
#define NKT1 (KHALF / BKB)   // 128 substeps per block

typedef __attribute__((ext_vector_type(8))) short bf16x8;
typedef __attribute__((ext_vector_type(4))) float f32x4;
typedef __attribute__((ext_vector_type(4))) unsigned short u16x4;
typedef __attribute__((ext_vector_type(8))) unsigned short u16x8;
typedef __attribute__((ext_vector_type(4))) unsigned int u32x4;

__device__ __forceinline__ unsigned short f2bf(float f) {
    uint32_t u = __builtin_bit_cast(uint32_t, f);
    u += 0x7fffu + ((u >> 16) & 1u);   // RNE; inputs are finite
    return (unsigned short)(u >> 16);
}

// Tiled transpose: neighT[c][r] = bf16(neigh[r][c]).
__global__ __launch_bounds__(256) void prep_transpose(const float* __restrict__ src,
                                                      unsigned short* __restrict__ dstT) {
    __shared__ unsigned short tl[128][66];
    const int t = threadIdx.x;
    const int r0 = blockIdx.x * 64;
#pragma unroll
    for (int i = 0; i < 8; ++i) {
        int idx = i * 256 + t;
        int r = idx >> 5;
        int s = idx & 31;
        f32x4 v = *(const f32x4*)(src + (size_t)(r0 + r) * 128 + s * 4);
#pragma unroll
        for (int j = 0; j < 4; ++j) tl[s * 4 + j][r] = f2bf(v[j]);
    }
    __syncthreads();
    const int c = t >> 1;
    const int half = t & 1;
#pragma unroll
    for (int j = 0; j < 4; ++j) {
        u16x8 p;
#pragma unroll
        for (int e = 0; e < 8; ++e) p[e] = tl[c][half * 32 + j * 8 + e];
        *(u16x8*)(dstT + (size_t)c * NN + r0 + half * 32 + j * 8) = p;
    }
}

#define MFMA16(a, b, c) __builtin_amdgcn_mfma_f32_16x16x32_bf16(a, b, c, 0, 0, 0)

#define BARRIER() do {                                          \
    asm volatile("s_waitcnt lgkmcnt(0)" ::: "memory");          \
    __builtin_amdgcn_s_barrier();                               \
    __builtin_amdgcn_sched_barrier(0);                          \
} while (0)

// K1: partial S (64 rows x 128 cols, k-half per block) -> atomicAdd into S.
// grid 512: row0 = (b>>1)*64, khalf = b&1. 2 blocks/CU.
__global__ __launch_bounds__(256, 2) void sage_partial(
    const float* __restrict__ adj,
    const unsigned short* __restrict__ neighT,
    float* __restrict__ S,            // d_out, pre-zeroed
    float* __restrict__ degW)         // [NN], pre-zeroed
{
    // LDS 64 KB: aL [2][64r][256B] swizzled, bL [2][128r][128B] swizzled.
    __shared__ __align__(16) char smem[65536];
    char* aL = smem;
    char* bL = smem + 32768;

    const int t = threadIdx.x;
    const int lane = t & 63;
    const int wv = t >> 6;
    const int mt = wv >> 1;
    const int nt = wv & 1;
    const size_t row0 = (size_t)(blockIdx.x >> 1) * BM;
    const size_t koff = (size_t)(blockIdx.x & 1) * KHALF;

    // A staging: 8 lanes/row; thread owns rows ra0 = t>>3 and ra0+32.
    const int ra0 = t >> 3;
    const int asl = t & 7;
    const float* aG0 = adj + (row0 + ra0) * (size_t)NN + koff + asl * 4;
    const float* aG1 = aG0 + (size_t)32 * NN;

    int awz[8];
#pragma unroll
    for (int i = 0; i < 8; ++i) {
        int row = (i < 4) ? ra0 : (ra0 + 32);
        int j = i & 3;
        awz[i] = row * 256 + ((j * 64 + asl * 8) ^ ((row & 7) << 4));
    }

    // B staging: 4 passes of 32 rows.
    const int br0 = t >> 3;
    const int bcs = (t & 7) * 8;
    const unsigned short* bG = neighT + (size_t)br0 * NN + koff + bcs;
    int bwb[4];
#pragma unroll
    for (int i = 0; i < 4; ++i) {
        int br = br0 + 32 * i;
        bwb[i] = (br * 128 + bcs * 2) ^ ((br & 7) << 4);
    }

    f32x4 acc[2][4];
#pragma unroll
    for (int i = 0; i < 2; ++i)
#pragma unroll
        for (int j = 0; j < 4; ++j) acc[i][j] = (f32x4){0.f, 0.f, 0.f, 0.f};

    float dsum[2] = {0.f, 0.f};

    f32x4 arA[8];
    u32x4 br_[4];

#define ISSUE_A(G) do {                                                       \
    _Pragma("unroll")                                                         \
    for (int i = 0; i < 8; ++i) {                                             \
        const float* p = (i < 4 ? aG0 : aG1) + (size_t)(G) * BKA + (i & 3) * 32; \
        arA[i] = __builtin_nontemporal_load((const f32x4*)p);                 \
    }                                                                         \
} while (0)

#define ISSUE_B(KT) do {                                                      \
    _Pragma("unroll")                                                         \
    for (int i = 0; i < 4; ++i)                                               \
        br_[i] = *(const u32x4*)(bG + (size_t)(32 * i) * NN +                 \
                                 (size_t)(KT) * BKB);                         \
} while (0)

#define STAGE_A(DST) do {                                                     \
    _Pragma("unroll")                                                         \
    for (int i = 0; i < 8; ++i) {                                             \
        f32x4 v = arA[i];                                                     \
        dsum[i >> 2] += (v[0] + v[1]) + (v[2] + v[3]);                        \
        u16x4 p; p.x = f2bf(v[0]); p.y = f2bf(v[1]);                          \
        p.z = f2bf(v[2]); p.w = f2bf(v[3]);                                   \
        *(u16x4*)((DST) + awz[i]) = p;                                        \
    }                                                                         \
} while (0)

#define STAGE_B(BUF) do {                                                     \
    char* bW = bL + (BUF) * 16384;                                            \
    _Pragma("unroll")                                                         \
    for (int i = 0; i < 4; ++i)                                               \
        *(u32x4*)(bW + bwb[i]) = br_[i];                                      \
} while (0)

#define COMPUTE(ABASE, SUB, BBUF) do {                                        \
    const char* aB = (ABASE);                                                 \
    const char* bB = bL + (BBUF) * 16384;                                     \
    _Pragma("unroll")                                                         \
    for (int ks = 0; ks < 2; ++ks) {                                          \
        bf16x8 af[2], bfr[4];                                                 \
        _Pragma("unroll")                                                     \
        for (int ms = 0; ms < 2; ++ms) {                                      \
            int r = mt * 32 + ms * 16 + (lane & 15);                          \
            int off = r * 256 + (((SUB) * 128 + ks * 64 + (lane >> 4) * 16)   \
                      ^ ((r & 7) << 4));                                      \
            af[ms] = *(const bf16x8*)(aB + off);                              \
        }                                                                     \
        _Pragma("unroll")                                                     \
        for (int ns = 0; ns < 4; ++ns) {                                      \
            int c = nt * 64 + ns * 16 + (lane & 15);                          \
            int off = c * 128 + ((ks * 64 + (lane >> 4) * 16)                 \
                      ^ ((c & 7) << 4));                                      \
            bfr[ns] = *(const bf16x8*)(bB + off);                             \
        }                                                                     \
        _Pragma("unroll")                                                     \
        for (int ms = 0; ms < 2; ++ms)                                        \
            _Pragma("unroll")                                                 \
            for (int ns = 0; ns < 4; ++ns)                                    \
                acc[ms][ns] = MFMA16(af[ms], bfr[ns], acc[ms][ns]);           \
    }                                                                         \
} while (0)

    // prologue
    ISSUE_B(0);
    ISSUE_A(0);
    STAGE_B(0);
    STAGE_A(aL);
    BARRIER();

    for (int g = 0; g < NG1; ++g) {
        char* aCur = aL + (g & 1) * 16384;
        char* aNxt = aL + ((g & 1) ^ 1) * 16384;
#pragma unroll
        for (int s = 0; s < 2; ++s) {
            const int kt = g * 2 + s;
            if (kt + 1 < NKT1) ISSUE_B(kt + 1);
            if (s == 0 && g + 1 < NG1) ISSUE_A(g + 1);
            COMPUTE(aCur, s, kt & 1);
            if (kt + 1 < NKT1) STAGE_B((kt + 1) & 1);
            if (s == 1 && g + 1 < NG1) STAGE_A(aNxt);
            BARRIER();
        }
    }

    // partial degree: 8-lane shfl tree, then one atomic per row
    dsum[0] += __shfl_xor(dsum[0], 1, 64);
    dsum[0] += __shfl_xor(dsum[0], 2, 64);
    dsum[0] += __shfl_xor(dsum[0], 4, 64);
    dsum[1] += __shfl_xor(dsum[1], 1, 64);
    dsum[1] += __shfl_xor(dsum[1], 2, 64);
    dsum[1] += __shfl_xor(dsum[1], 4, 64);
    if (asl == 0) {
        atomicAdd(&degW[row0 + ra0], dsum[0]);
        atomicAdd(&degW[row0 + ra0 + 32], dsum[1]);
    }

    // partial S -> atomicAdd (device scope), coalesced along cols
#pragma unroll
    for (int ms = 0; ms < 2; ++ms)
#pragma unroll
        for (int ns = 0; ns < 4; ++ns)
#pragma unroll
            for (int j = 0; j < 4; ++j) {
                int r = mt * 32 + ms * 16 + (lane >> 4) * 4 + j;
                int c = nt * 64 + ns * 16 + (lane & 15);
                atomicAdd(&S[(row0 + r) * 128 + c], acc[ms][ns][j]);
            }
}

// K2: out = [feat | S/(deg+1)] @ W^T, overwriting S (=d_out) in place.
__global__ __launch_bounds__(256) void sage_epilogue(
    const float* __restrict__ feat,
    const float* __restrict__ W,
    const float* __restrict__ degW,
    float* __restrict__ S)            // read S, write out (same buffer)
{
    __shared__ __align__(16) char smem[33024];
    char* dL = smem;                       // [64][512 B] bf16 swizzled
    float* degp = (float*)(smem + 32768);  // [64]

    const int t = threadIdx.x;
    const int lane = t & 63;
    const int wv = t >> 6;
    const int mt = wv >> 1;
    const int nt = wv & 1;
    const size_t row0 = (size_t)blockIdx.x * BM;

    if (t < 64) degp[t] = degW[row0 + t];

    // feat -> cols [0,128)
#pragma unroll
    for (int i = 0; i < 8; ++i) {
        int idx = i * 256 + t;
        int r = idx >> 5;
        int s = idx & 31;
        f32x4 v = *(const f32x4*)(feat + (row0 + r) * 128 + s * 4);
        u16x4 p; p.x = f2bf(v[0]); p.y = f2bf(v[1]); p.z = f2bf(v[2]); p.w = f2bf(v[3]);
        int off = (r * 512 + s * 8) ^ ((r & 7) << 4);
        *(u16x4*)(dL + off) = p;
    }
    __syncthreads();   // degp visible

    // S/(deg+1) -> cols [128,256)
#pragma unroll
    for (int i = 0; i < 8; ++i) {
        int idx = i * 256 + t;
        int r = idx >> 5;
        int s = idx & 31;
        f32x4 v = *(const f32x4*)(S + (row0 + r) * 128 + s * 4);
        float inv = 1.0f / (degp[r] + 1.0f);
        u16x4 p; p.x = f2bf(v[0] * inv); p.y = f2bf(v[1] * inv);
        p.z = f2bf(v[2] * inv); p.w = f2bf(v[3] * inv);
        int off = (r * 512 + 256 + s * 8) ^ ((r & 7) << 4);
        *(u16x4*)(dL + off) = p;
    }
    __syncthreads();

    f32x4 acc2[2][4];
#pragma unroll
    for (int i = 0; i < 2; ++i)
#pragma unroll
        for (int j = 0; j < 4; ++j) acc2[i][j] = (f32x4){0.f, 0.f, 0.f, 0.f};

#pragma unroll
    for (int ks = 0; ks < 8; ++ks) {
        bf16x8 af[2], bfr[4];
#pragma unroll
        for (int ms = 0; ms < 2; ++ms) {
            int r = mt * 32 + ms * 16 + (lane & 15);
            int off = r * 512 + ((ks * 64 + (lane >> 4) * 16) ^ ((r & 7) << 4));
            af[ms] = *(const bf16x8*)(dL + off);
        }
#pragma unroll
        for (int ns = 0; ns < 4; ++ns) {
            int c = nt * 64 + ns * 16 + (lane & 15);
            int k0 = ks * 32 + (lane >> 4) * 8;
            f32x4 w0 = *(const f32x4*)(W + (size_t)c * 256 + k0);
            f32x4 w1 = *(const f32x4*)(W + (size_t)c * 256 + k0 + 4);
            u16x8 p;
            p[0] = f2bf(w0[0]); p[1] = f2bf(w0[1]); p[2] = f2bf(w0[2]); p[3] = f2bf(w0[3]);
            p[4] = f2bf(w1[0]); p[5] = f2bf(w1[1]); p[6] = f2bf(w1[2]); p[7] = f2bf(w1[3]);
            bfr[ns] = __builtin_bit_cast(bf16x8, p);
        }
#pragma unroll
        for (int ms = 0; ms < 2; ++ms)
#pragma unroll
            for (int ns = 0; ns < 4; ++ns)
                acc2[ms][ns] = MFMA16(af[ms], bfr[ns], acc2[ms][ns]);
    }

    // overwrite S rows with final output (this block read them above)
#pragma unroll
    for (int ms = 0; ms < 2; ++ms)
#pragma unroll
        for (int ns = 0; ns < 4; ++ns)
#pragma unroll
            for (int j = 0; j < 4; ++j) {
                int r = mt * 32 + ms * 16 + (lane >> 4) * 4 + j;
                int c = nt * 64 + ns * 16 + (lane & 15);
                S[(row0 + r) * 128 + c] = acc2[ms][ns][j];
            }
}

extern "C" void kernel_launch(void* const* d_in, const int* in_sizes, int n_in,
                              void* d_out, int out_size, void* d_ws, size_t ws_size,
                              hipStream_t stream) {
    const float* adj = (const float*)d_in[0];
    const float* feat = (const float*)d_in[1];
    const float* neigh = (const float*)d_in[2];
    const float* W = (const float*)d_in[3];
    float* S = (float*)d_out;                              // S partial, then final out
    unsigned short* neighT = (unsigned short*)d_ws;        // 4 MiB
    float* degW = (float*)((char*)d_ws + (size_t)4 * 1024 * 1024);  // 64 KiB

    hipMemsetAsync(d_out, 0, (size_t)NN * 128 * sizeof(float), stream);
    hipMemsetAsync(degW, 0, (size_t)NN * sizeof(float), stream);
    prep_transpose<<<NN / 64, 256, 0, stream>>>(neigh, neighT);
    sage_partial<<<(NN / BM) * 2, 256, 0, stream>>>(adj, neighT, S, degW);
    sage_epilogue<<<NN / BM, 256, 0, stream>>>(feat, W, degW, S);
}